// Round 10
// baseline (265.290 us; speedup 1.0000x reference)
//
#include <hip/hip_runtime.h>

using short8 = __attribute__((ext_vector_type(8))) short;
using f32x4  = __attribute__((ext_vector_type(4))) float;

__device__ __forceinline__ unsigned short f2bf(float x){
    unsigned u = __float_as_uint(x);
    unsigned r = (u + 0x7FFFu + ((u>>16)&1u)) >> 16;
    return (unsigned short)r;
}
__device__ __forceinline__ float bf2f(unsigned short h){
    return __uint_as_float(((unsigned)h)<<16);
}
__device__ __forceinline__ float sigf(float x){ return 1.0f/(1.0f+__expf(-x)); }
// XOR swizzle: flip byte bits 4-6 with bits 7-9 (bijective within each 1KB block)
__device__ __forceinline__ int swz(int b){ return b ^ (((b>>7)&7)<<4); }

struct SP {
    const float *x;
    const float *g1,*be1,*m1,*v1;
    const float *g2,*be2,*m2,*v2;
    const float *g3,*be3,*m3,*v3;
    // raw weights (for stage-0 fold + stage-0 L1 direct path)
    const float *U1r,*W1r,*U2r,*W2r,*U3r,*W3r,*b1r,*b2r,*b3r;
    unsigned short *hs1,*hs2,*hs3;
    unsigned short *pl1,*pl2,*pl3;   // pooled outputs (bf16, [n][t][y][x][f])
    float *cst1,*cst2,*cst3;         // cell state, fragment-native [tile][f][col]
    short8 *U1b,*W1b,*U2b,*W2b,*U3b,*W3b;
    float *bp;
    unsigned *ctr;
};

// ---------------- weight/bias transform item (run inside stage 0) ----------------
__device__ __forceinline__ void xform_item(int i, const SP& p)
{
    if (i >= 49536) return;
    if (i >= 49152) {                      // permuted biases, 3 layers x 128
        int j = i - 49152, layer = j >> 7, np = j & 127;
        int oc = ((np>>4)&3)*32 + (np>>6)*16 + (np&15);
        const float* bs = layer==0 ? p.b1r : (layer==1 ? p.b2r : p.b3r);
        p.bp[j] = bs[oc];
        return;
    }
    const float* src; short8* dst; int base, kmax;
    if      (i < 12800){ src=p.U1r; dst=p.U1b; base=0;     kmax=800; }
    else if (i < 14336){ src=p.W1r; dst=p.W1b; base=12800; kmax=75;  }
    else if (i < 27136){ src=p.U2r; dst=p.U2b; base=14336; kmax=800; }
    else if (i < 39936){ src=p.W2r; dst=p.W2b; base=27136; kmax=800; }
    else if (i < 44544){ src=p.U3r; dst=p.U3b; base=39936; kmax=288; }
    else               { src=p.W3r; dst=p.W3b; base=44544; kmax=288; }
    int j = i - base;
    int lane = j & 63, nt = (j >> 6) & 7, tap = j >> 9;
    int np = nt*16 + (lane & 15);
    int oc = ((np>>4)&3)*32 + (np>>6)*16 + (np&15);
    int g = lane >> 4;
    short8 pk;
    #pragma unroll
    for (int e = 0; e < 8; ++e) {
        int k = tap*32 + g*8 + e;
        unsigned short v = (k < kmax) ? f2bf(src[(long)k*128 + oc]) : (unsigned short)0;
        pk[e] = (short)v;
    }
    dst[j] = pk;
}

// ---------------- generic double-buffered tap loop ----------------
template<int K, int PW, int MT2>
__device__ __forceinline__ void conv_taps(f32x4 (&acc)[MT2][4],
    const unsigned short* patch, const short8* Wf, int mh, int nh, int l15, int g4, int lane)
{
    constexpr int NTAP = K*K;
    const short8* ub = Wf + nh*4*64 + lane;
    short8 bA0 = ub[0], bA1 = ub[64], bA2 = ub[128], bA3 = ub[192];
    short8 bB0 = bA0, bB1 = bA1, bB2 = bA2, bB3 = bA3;
    { const short8* u = ub + 512; bB0=u[0]; bB1=u[64]; bB2=u[128]; bB3=u[192]; }
    #pragma unroll 1
    for (int tp = 0; tp < NTAP; tp += 2) {
        {
            int dy = tp / K, dx = tp % K;
            #pragma unroll
            for (int mt = 0; mt < MT2; ++mt) {
                short8 af = *(const short8*)((const char*)patch +
                    swz(((mh*MT2 + mt + dy)*PW + l15 + dx)*64 + g4*16));
                acc[mt][0] = __builtin_amdgcn_mfma_f32_16x16x32_bf16(af, bA0, acc[mt][0], 0,0,0);
                acc[mt][1] = __builtin_amdgcn_mfma_f32_16x16x32_bf16(af, bA1, acc[mt][1], 0,0,0);
                acc[mt][2] = __builtin_amdgcn_mfma_f32_16x16x32_bf16(af, bA2, acc[mt][2], 0,0,0);
                acc[mt][3] = __builtin_amdgcn_mfma_f32_16x16x32_bf16(af, bA3, acc[mt][3], 0,0,0);
            }
            if (tp + 2 < NTAP) { const short8* u = ub + (long)(tp+2)*512; bA0=u[0];bA1=u[64];bA2=u[128];bA3=u[192]; }
        }
        if (tp + 1 < NTAP) {
            int dy = (tp+1) / K, dx = (tp+1) % K;
            #pragma unroll
            for (int mt = 0; mt < MT2; ++mt) {
                short8 af = *(const short8*)((const char*)patch +
                    swz(((mh*MT2 + mt + dy)*PW + l15 + dx)*64 + g4*16));
                acc[mt][0] = __builtin_amdgcn_mfma_f32_16x16x32_bf16(af, bB0, acc[mt][0], 0,0,0);
                acc[mt][1] = __builtin_amdgcn_mfma_f32_16x16x32_bf16(af, bB1, acc[mt][1], 0,0,0);
                acc[mt][2] = __builtin_amdgcn_mfma_f32_16x16x32_bf16(af, bB2, acc[mt][2], 0,0,0);
                acc[mt][3] = __builtin_amdgcn_mfma_f32_16x16x32_bf16(af, bB3, acc[mt][3], 0,0,0);
            }
            if (tp + 3 < NTAP) { const short8* u = ub + (long)(tp+3)*512; bB0=u[0];bB1=u[64];bB2=u[128];bB3=u[192]; }
        }
    }
}

// ---------------- shared epilogue: LSTM gates + cell (frag-native) + h + pool/BN ----------------
template<int MT2>
__device__ __forceinline__ void lstm_epilogue(
    f32x4 (&acc)[MT2][4], unsigned short* hs, float* cst, unsigned short* plout,
    const float* gg, const float* bb, const float* mm, const float* vv,
    int H, int W, int n, int y0, int x0, int t, int mh, int nh, int l15, int g4, int first)
{
    const int f = nh*16 + l15;
    const int xt = x0 >> 4;
    const float sc = gg[f] * rsqrtf(vv[f] + 1e-3f);
    const float sh = bb[f] - mm[f]*sc;
    unsigned short* outh = hs + ((long)n*10 + t)*(long)H*W*32;
    float hv[MT2][4];
    #pragma unroll
    for (int mt = 0; mt < MT2; ++mt) {
        int row = y0 + mh*MT2 + mt;
        long tb = ((long)(n*H + row)*(W>>4) + xt)*512 + f*16 + g4*4;
        f32x4 cold = first ? (f32x4){0.f,0.f,0.f,0.f} : *(const f32x4*)&cst[tb];
        f32x4 cn;
        #pragma unroll
        for (int j = 0; j < 4; ++j) {
            float zi = acc[mt][0][j];
            float zf = acc[mt][1][j];
            float zg = acc[mt][2][j];
            float zo = acc[mt][3][j];
            float c2 = sigf(zf)*cold[j] + sigf(zi)*fmaxf(zg, 0.0f);
            cn[j] = c2;
            float h = sigf(zo)*fmaxf(c2, 0.0f);
            hv[mt][j] = h;
            outh[((long)row*W + (x0 + g4*4 + j))*32 + f] = f2bf(h);
        }
        *(f32x4*)&cst[tb] = cn;
    }
    #pragma unroll
    for (int mp = 0; mp < MT2/2; ++mp) {
        int orow = (y0>>1) + mh*(MT2/2) + mp;
        #pragma unroll
        for (int jp = 0; jp < 2; ++jp) {
            int ocol = (x0>>1) + g4*2 + jp;
            float mx = fmaxf(fmaxf(hv[2*mp][2*jp],   hv[2*mp][2*jp+1]),
                             fmaxf(hv[2*mp+1][2*jp], hv[2*mp+1][2*jp+1]));
            plout[(((long)(n*10 + t)*(H>>1) + orow)*(W>>1) + ocol)*32 + f] = f2bf(mx*sc + sh);
        }
    }
}

// ---------------- L1 step (TH=4): fused im2col x-conv + recurrent conv + gates ----------------
// t==0 path reads RAW W1/b1 (fragment buffers not yet built in this launch).
__device__ void l1_step(char* smem, const SP& p, int n, int y0, int x0, int t)
{
    constexpr int PAD = 2, PH = 8, PW = 20, MT2 = 2, MPX = 64;
    const int H = 64, W = 64;
    unsigned short* patch_s = (unsigned short*)smem;                // 10240 B
    unsigned short* xpk_s   = (unsigned short*)(smem + 10240);      // 12288 B
    const int tid = threadIdx.x;
    const int lane = tid & 63, wid = tid >> 6;
    const int mh = wid >> 1, nh = wid & 1;
    const int l15 = lane & 15, g4 = lane >> 4;
    const int first = (t == 0);

    // zero-fill im2col pad region (k slots 75..95 must be 0)
    short8 z8 = {0,0,0,0,0,0,0,0};
    #pragma unroll
    for (int c = tid; c < MPX*96/8; c += 256)
        ((short8*)xpk_s)[c] = z8;

    // stage h patch (t>0)
    if (!first) {
        const unsigned short* s = p.hs1 + ((long)n*10 + (t-1))*(long)H*W*32;
        #pragma unroll 2
        for (int c = tid; c < PH*PW*4; c += 256) {
            int pix = c >> 2, gq = c & 3;
            int pr = pix / PW, pc = pix % PW;
            int gy = y0 - PAD + pr, gx = x0 - PAD + pc;
            short8 v = z8;
            if ((unsigned)gy < 64u && (unsigned)gx < 64u)
                v = *(const short8*)(s + ((long)gy*W + gx)*32 + gq*8);
            *(short8*)((char*)patch_s + swz(pix*64 + gq*16)) = v;
        }
    }
    __syncthreads();
    // x im2col scatter: thread owns pixel px, strides taps
    {
        const float* xs = p.x + ((long)n*10 + t)*4096*3;
        const int px = tid & 63;
        const int prow = px >> 4, pcol = px & 15;
        #pragma unroll 2
        for (int tap = tid >> 6; tap < 25; tap += 4) {
            int dy = (tap*52) >> 8, dx = tap - dy*5;   // dy = tap/5 via mul-shift
            int gy = y0 + prow - PAD + dy;
            int gx = x0 + pcol - PAD + dx;
            float v0=0.f, v1=0.f, v2=0.f;
            if ((unsigned)gy < 64u && (unsigned)gx < 64u) {
                const float* b = xs + ((long)gy*64 + gx)*3;
                v0 = b[0]; v1 = b[1]; v2 = b[2];
            }
            int o = px*192 + tap*6;
            *(unsigned short*)((char*)xpk_s + swz(o))   = f2bf(v0);
            *(unsigned short*)((char*)xpk_s + swz(o+2)) = f2bf(v1);
            *(unsigned short*)((char*)xpk_s + swz(o+4)) = f2bf(v2);
        }
    }
    __syncthreads();

    f32x4 acc[MT2][4];
    #pragma unroll
    for (int ntl = 0; ntl < 4; ++ntl) {
        float bv;
        if (first) {
            int np = (nh*4+ntl)*16 + l15;
            int oc = ((np>>4)&3)*32 + (np>>6)*16 + (np&15);
            bv = p.b1r[oc];
        } else {
            bv = p.bp[(nh*4+ntl)*16 + l15];
        }
        #pragma unroll
        for (int mt = 0; mt < MT2; ++mt)
            acc[mt][ntl] = (f32x4){bv,bv,bv,bv};
    }
    // x-conv: 3 padded K-chunks
    if (first) {
        // raw-W1 path (fragments not built yet in this launch)
        #pragma unroll 1
        for (int c = 0; c < 3; ++c) {
            short8 bfr[4];
            #pragma unroll
            for (int ntl = 0; ntl < 4; ++ntl) {
                int np = (nh*4+ntl)*16 + l15;
                int oc = ((np>>4)&3)*32 + (np>>6)*16 + (np&15);
                short8 bf;
                #pragma unroll
                for (int e = 0; e < 8; ++e) {
                    int k = c*32 + g4*8 + e;
                    bf[e] = (k < 75) ? (short)f2bf(p.W1r[(long)k*128 + oc]) : (short)0;
                }
                bfr[ntl] = bf;
            }
            #pragma unroll
            for (int mt = 0; mt < MT2; ++mt) {
                short8 af = *(const short8*)((const char*)xpk_s +
                    swz(((mh*MT2+mt)*16 + l15)*192 + c*64 + g4*16));
                acc[mt][0] = __builtin_amdgcn_mfma_f32_16x16x32_bf16(af, bfr[0], acc[mt][0], 0,0,0);
                acc[mt][1] = __builtin_amdgcn_mfma_f32_16x16x32_bf16(af, bfr[1], acc[mt][1], 0,0,0);
                acc[mt][2] = __builtin_amdgcn_mfma_f32_16x16x32_bf16(af, bfr[2], acc[mt][2], 0,0,0);
                acc[mt][3] = __builtin_amdgcn_mfma_f32_16x16x32_bf16(af, bfr[3], acc[mt][3], 0,0,0);
            }
        }
    } else {
        #pragma unroll 1
        for (int c = 0; c < 3; ++c) {
            const short8* wp = p.W1b + ((long)c*8 + nh*4)*64 + lane;
            short8 bf0 = wp[0], bf1 = wp[64], bf2 = wp[128], bf3 = wp[192];
            #pragma unroll
            for (int mt = 0; mt < MT2; ++mt) {
                short8 af = *(const short8*)((const char*)xpk_s +
                    swz(((mh*MT2+mt)*16 + l15)*192 + c*64 + g4*16));
                acc[mt][0] = __builtin_amdgcn_mfma_f32_16x16x32_bf16(af, bf0, acc[mt][0], 0,0,0);
                acc[mt][1] = __builtin_amdgcn_mfma_f32_16x16x32_bf16(af, bf1, acc[mt][1], 0,0,0);
                acc[mt][2] = __builtin_amdgcn_mfma_f32_16x16x32_bf16(af, bf2, acc[mt][2], 0,0,0);
                acc[mt][3] = __builtin_amdgcn_mfma_f32_16x16x32_bf16(af, bf3, acc[mt][3], 0,0,0);
            }
        }
    }
    if (!first)
        conv_taps<5,PW,MT2>(acc, patch_s, p.U1b, mh, nh, l15, g4, lane);

    lstm_epilogue<MT2>(acc, p.hs1, p.cst1, p.pl1, p.g1, p.be1, p.m1, p.v1,
                       H, W, n, y0, x0, t, mh, nh, l15, g4, first);
}

// ---------------- L2/L3 step: dual conv (W ⊛ pooled_prev + U ⊛ h_prev) + gates ----------------
template<int K, int HH>
__device__ void l23_step(char* smem, const SP& p,
    unsigned short* hs, const unsigned short* plin, unsigned short* plout, float* cst,
    const short8* Ufr, const short8* Wfr, const float* bp,
    const float* gg, const float* bb, const float* mm, const float* vv,
    int n, int y0, int x0, int t)
{
    constexpr int TH = 4, PAD = K/2, PH = TH+K-1, PW = 16+K-1, MT2 = 2;
    const int H = HH, W = HH;
    unsigned short* patchH = (unsigned short*)smem;
    unsigned short* patchX = (unsigned short*)(smem + PH*PW*64);

    const int tid = threadIdx.x;
    const int lane = tid & 63, wid = tid >> 6;
    const int mh = wid >> 1, nh = wid & 1;
    const int l15 = lane & 15, g4 = lane >> 4;
    const int first = (t == 0);

    const unsigned short* hsrc = hs + ((long)n*10 + (t-1))*(long)H*W*32;
    const unsigned short* xsrc = plin + ((long)n*10 + t)*(long)H*W*32;
    short8 z8 = {0,0,0,0,0,0,0,0};
    #pragma unroll 2
    for (int c = tid; c < PH*PW*4; c += 256) {
        int pix = c >> 2, gq = c & 3;
        int pr = pix / PW, pc = pix % PW;
        int gy = y0 - PAD + pr, gx = x0 - PAD + pc;
        short8 vx = z8, vh = z8;
        if ((unsigned)gy < (unsigned)H && (unsigned)gx < (unsigned)W) {
            vx = *(const short8*)(xsrc + ((long)gy*W + gx)*32 + gq*8);
            if (!first) vh = *(const short8*)(hsrc + ((long)gy*W + gx)*32 + gq*8);
        }
        *(short8*)((char*)patchX + swz(pix*64 + gq*16)) = vx;
        *(short8*)((char*)patchH + swz(pix*64 + gq*16)) = vh;
    }
    __syncthreads();

    f32x4 acc[MT2][4];
    #pragma unroll
    for (int ntl = 0; ntl < 4; ++ntl) {
        float bv = bp[(nh*4+ntl)*16 + l15];
        #pragma unroll
        for (int mt = 0; mt < MT2; ++mt)
            acc[mt][ntl] = (f32x4){bv,bv,bv,bv};
    }
    conv_taps<K,PW,MT2>(acc, patchX, Wfr, mh, nh, l15, g4, lane);
    if (!first) conv_taps<K,PW,MT2>(acc, patchH, Ufr, mh, nh, l15, g4, lane);

    lstm_epilogue<MT2>(acc, hs, cst, plout, gg, bb, mm, vv,
                       H, W, n, y0, x0, t, mh, nh, l15, g4, first);
}

// ---------------- pipelined stage kernel: L2[s-1] | L3[s-2] | L1[s] ----------------
// Stage 0: L2/L3 slots are idle -> they run the weight transform (and ctr reset).
__global__ __launch_bounds__(256, 2)
void stage_k(SP p, int s)
{
    __shared__ __align__(16) char smem[22528];
    const int bid = blockIdx.x;
    if (bid < 128) {                       // L2 (heaviest) dispatches first
        int t = s - 1;
        if (t >= 0 && t < 10) {
            int n = bid >> 4, rem = bid & 15;
            l23_step<5,32>(smem, p, p.hs2, p.pl1, p.pl2, p.cst2,
                           p.U2b, p.W2b, p.bp + 128,
                           p.g2, p.be2, p.m2, p.v2,
                           n, (rem >> 1)*4, (rem & 1)*16, t);
        } else if (s == 0) {
            if (bid == 0 && threadIdx.x == 0)
                __hip_atomic_store(p.ctr, 0u, __ATOMIC_RELEASE, __HIP_MEMORY_SCOPE_AGENT);
            for (int i = bid*256 + threadIdx.x; i < 49536; i += 160*256)
                xform_item(i, p);
        }
    } else if (bid < 160) {                // L3
        int t = s - 2;
        if (t >= 0 && t < 10) {
            int idx = bid - 128;
            int n = idx >> 2, rem = idx & 3;
            l23_step<3,16>(smem, p, p.hs3, p.pl2, p.pl3, p.cst3,
                           p.U3b, p.W3b, p.bp + 256,
                           p.g3, p.be3, p.m3, p.v3,
                           n, rem*4, 0, t);
        } else if (s == 0) {
            for (int i = bid*256 + threadIdx.x; i < 49536; i += 160*256)
                xform_item(i, p);
        }
    } else {                               // L1 (lightest, bulk)
        int t = s;
        if (t < 10) {
            int idx = bid - 160;
            int n = idx >> 6, rem = idx & 63;
            l1_step(smem, p, n, (rem >> 2)*4, (rem & 3)*16, t);
        }
    }
}

// ---------------- dense: K-split partial GEMM + last-block tail ----------------
__global__ __launch_bounds__(256)
void dense_all(const unsigned short* __restrict__ flat, const float* __restrict__ Wd1,
               const float* __restrict__ bd1, const float* __restrict__ Wd2,
               const float* __restrict__ bd2, float* __restrict__ partial,
               unsigned* __restrict__ ctr, float* __restrict__ outp)
{
    __shared__ __align__(16) float xs[2048];
    __shared__ unsigned rank_s;
    const int kc = blockIdx.x, k0 = kc*256;
    const int t = threadIdx.x;
    {
        int r = t >> 5, kb = (t & 31)*8;
        short8 v = *(const short8*)(flat + (long)r*20480 + k0 + kb);
        #pragma unroll
        for (int e = 0; e < 8; ++e) xs[(kb+e)*8 + r] = bf2f((unsigned short)v[e]);
    }
    __syncthreads();
    const int c = t & 63, seg = t >> 6;
    f32x4 accA = {0,0,0,0}, accB = {0,0,0,0};
    #pragma unroll 4
    for (int kk = seg*64; kk < seg*64 + 64; ++kk) {
        float w = Wd1[(long)(k0+kk)*64 + c];
        f32x4 xa = *(const f32x4*)&xs[kk*8];
        f32x4 xb = *(const f32x4*)&xs[kk*8 + 4];
        #pragma unroll
        for (int j = 0; j < 4; ++j) { accA[j] = fmaf(xa[j], w, accA[j]); accB[j] = fmaf(xb[j], w, accB[j]); }
    }
    __syncthreads();
    #pragma unroll
    for (int j = 0; j < 4; ++j) {
        xs[(seg*8 + j)*64 + c]     = accA[j];
        xs[(seg*8 + 4 + j)*64 + c] = accB[j];
    }
    __syncthreads();
    #pragma unroll
    for (int o = t; o < 512; o += 256) {
        int r = o >> 6, cc = o & 63;
        partial[(long)kc*512 + o] = (xs[(0*8+r)*64+cc] + xs[(1*8+r)*64+cc])
                                  + (xs[(2*8+r)*64+cc] + xs[(3*8+r)*64+cc]);
    }
    __syncthreads();
    if (t == 0) {
        __builtin_amdgcn_fence(__ATOMIC_RELEASE, "agent");
        rank_s = __hip_atomic_fetch_add(ctr, 1u, __ATOMIC_ACQ_REL, __HIP_MEMORY_SCOPE_AGENT);
    }
    __syncthreads();
    if (rank_s != 79) return;
    __builtin_amdgcn_fence(__ATOMIC_ACQUIRE, "agent");

    float* d1  = xs;            // 512
    float* l2s = xs + 512;      // 80
    #pragma unroll
    for (int rr = 0; rr < 2; ++rr) {
        int idx = rr*256 + t;
        int cc = idx & 63;
        float s = bd1[cc];
        #pragma unroll 4
        for (int q = 0; q < 80; ++q) s += partial[q*512 + idx];
        float mx = s;
        for (int o = 32; o > 0; o >>= 1) mx = fmaxf(mx, __shfl_xor(mx, o, 64));
        float e = __expf(s - mx);
        float sm = e;
        for (int o = 32; o > 0; o >>= 1) sm += __shfl_xor(sm, o, 64);
        d1[idx] = e / sm;
    }
    __syncthreads();
    if (t < 80) {
        int r = t / 10, o = t % 10;
        float l = bd2[o];
        #pragma unroll 8
        for (int cc = 0; cc < 64; ++cc) l = fmaf(d1[r*64 + cc], Wd2[cc*10 + o], l);
        l2s[t] = l;
    }
    __syncthreads();
    if (t < 8) {
        float mx2 = l2s[t*10];
        #pragma unroll
        for (int j = 1; j < 10; ++j) mx2 = fmaxf(mx2, l2s[t*10 + j]);
        float ev[10], s2 = 0.f;
        #pragma unroll
        for (int j = 0; j < 10; ++j) { ev[j] = __expf(l2s[t*10 + j] - mx2); s2 += ev[j]; }
        #pragma unroll
        for (int j = 0; j < 10; ++j) outp[t*10 + j] = ev[j] / s2;
    }
}

extern "C" void kernel_launch(void* const* d_in, const int* in_sizes, int n_in,
                              void* d_out, int out_size, void* d_ws, size_t ws_size,
                              hipStream_t stream)
{
    const float* Wd1 = (const float*)d_in[22];
    const float* bd1 = (const float*)d_in[23];
    const float* Wd2 = (const float*)d_in[24];
    const float* bd2 = (const float*)d_in[25];

    char* ws = (char*)d_ws;
    SP p;
    p.x   = (const float*)d_in[0];
    p.g1  = (const float*)d_in[4];  p.be1 = (const float*)d_in[5];  p.m1 = (const float*)d_in[6];  p.v1 = (const float*)d_in[7];
    p.g2  = (const float*)d_in[11]; p.be2 = (const float*)d_in[12]; p.m2 = (const float*)d_in[13]; p.v2 = (const float*)d_in[14];
    p.g3  = (const float*)d_in[18]; p.be3 = (const float*)d_in[19]; p.m3 = (const float*)d_in[20]; p.v3 = (const float*)d_in[21];
    p.U1r = (const float*)d_in[2];  p.W1r = (const float*)d_in[1];  p.b1r = (const float*)d_in[3];
    p.U2r = (const float*)d_in[9];  p.W2r = (const float*)d_in[8];  p.b2r = (const float*)d_in[10];
    p.U3r = (const float*)d_in[16]; p.W3r = (const float*)d_in[15]; p.b3r = (const float*)d_in[17];

    p.hs1 = (unsigned short*)(ws);                  // 20,971,520
    p.hs2 = (unsigned short*)(ws + 20971520);       //  5,242,880
    p.hs3 = (unsigned short*)(ws + 26214400);       //  1,310,720
    p.cst1 = (float*)(ws + 27525120);               //  4,194,304
    p.cst2 = (float*)(ws + 31719424);               //  1,048,576
    p.cst3 = (float*)(ws + 32768000);               //    262,144
    p.pl1 = (unsigned short*)(ws + 33030144);       //  5,242,880
    p.pl2 = (unsigned short*)(ws + 38273024);       //  1,310,720
    p.pl3 = (unsigned short*)(ws + 39583744);       //    327,680
    p.U1b = (short8*)(ws + 39911424);               //    204,800
    p.W1b = (short8*)(ws + 40116224);               //     24,576
    p.U2b = (short8*)(ws + 40140800);               //    204,800
    p.W2b = (short8*)(ws + 40345600);               //    204,800
    p.U3b = (short8*)(ws + 40550400);               //     73,728
    p.W3b = (short8*)(ws + 40624128);               //     73,728
    p.bp  = (float*)(ws + 40697856);                //      1,536
    float* partial = (float*)(ws + 40699392);       //    163,840
    p.ctr = (unsigned*)(ws + 40863232);             //     64 B

    for (int s = 0; s < 12; ++s)
        stage_k<<<672, 256, 0, stream>>>(p, s);

    dense_all<<<80, 256, 0, stream>>>(p.pl3, Wd1, bd1, Wd2, bd2, partial,
                                      p.ctr, (float*)d_out);
}

// Round 11
// 223.814 us; speedup vs baseline: 1.1853x; 1.1853x over previous
//
#include <hip/hip_runtime.h>

using short8 = __attribute__((ext_vector_type(8))) short;
using f32x4  = __attribute__((ext_vector_type(4))) float;

__device__ __forceinline__ unsigned short f2bf(float x){
    unsigned u = __float_as_uint(x);
    unsigned r = (u + 0x7FFFu + ((u>>16)&1u)) >> 16;
    return (unsigned short)r;
}
__device__ __forceinline__ float bf2f(unsigned short h){
    return __uint_as_float(((unsigned)h)<<16);
}
__device__ __forceinline__ float sigf(float x){ return 1.0f/(1.0f+__expf(-x)); }
// XOR swizzle: flip byte bits 4-6 with bits 7-9 (bijective within each 1KB block)
__device__ __forceinline__ int swz(int b){ return b ^ (((b>>7)&7)<<4); }

struct SP {
    const float *x;
    const float *g1,*be1,*m1,*v1;
    const float *g2,*be2,*m2,*v2;
    const float *g3,*be3,*m3,*v3;
    unsigned short *hs1,*hs2,*hs3;
    unsigned short *pl1,*pl2,*pl3;   // pooled outputs (bf16, [n][t][y][x][f])
    float *cst1,*cst2,*cst3;         // cell state, fragment-native [tile][f][col]
    const short8 *U1b,*W1b,*U2b,*W2b,*U3b,*W3b;
    const float *bp;
    unsigned *ctr;
};

// ---------------- weight/bias transform into MFMA fragment layout ----------------
__global__ __launch_bounds__(256)
void xform_all(const float* __restrict__ U1, const float* __restrict__ W1,
               const float* __restrict__ U2, const float* __restrict__ W2,
               const float* __restrict__ U3, const float* __restrict__ W3,
               const float* __restrict__ b1, const float* __restrict__ b2, const float* __restrict__ b3,
               short8* __restrict__ U1b, short8* __restrict__ W1b,
               short8* __restrict__ U2b, short8* __restrict__ W2b,
               short8* __restrict__ U3b, short8* __restrict__ W3b,
               float* __restrict__ bp)
{
    int i = blockIdx.x*256 + threadIdx.x;
    if (i >= 49536) return;
    if (i >= 49152) {                      // permuted biases, 3 layers x 128
        int j = i - 49152, layer = j >> 7, np = j & 127;
        int oc = ((np>>4)&3)*32 + (np>>6)*16 + (np&15);
        const float* bs = layer==0 ? b1 : (layer==1 ? b2 : b3);
        bp[j] = bs[oc];
        return;
    }
    const float* src; short8* dst; int base, kmax;
    if      (i < 12800){ src=U1; dst=U1b; base=0;     kmax=800; }
    else if (i < 14336){ src=W1; dst=W1b; base=12800; kmax=75;  }
    else if (i < 27136){ src=U2; dst=U2b; base=14336; kmax=800; }
    else if (i < 39936){ src=W2; dst=W2b; base=27136; kmax=800; }
    else if (i < 44544){ src=U3; dst=U3b; base=39936; kmax=288; }
    else               { src=W3; dst=W3b; base=44544; kmax=288; }
    int j = i - base;
    int lane = j & 63, nt = (j >> 6) & 7, tap = j >> 9;
    int np = nt*16 + (lane & 15);
    int oc = ((np>>4)&3)*32 + (np>>6)*16 + (np&15);
    int g = lane >> 4;
    short8 pk;
    #pragma unroll
    for (int e = 0; e < 8; ++e) {
        int k = tap*32 + g*8 + e;
        unsigned short v = (k < kmax) ? f2bf(src[(long)k*128 + oc]) : (unsigned short)0;
        pk[e] = (short)v;
    }
    dst[j] = pk;
}

// ---------------- generic double-buffered tap loop ----------------
template<int K, int PW, int MT2>
__device__ __forceinline__ void conv_taps(f32x4 (&acc)[MT2][4],
    const unsigned short* patch, const short8* Wf, int mh, int nh, int l15, int g4, int lane)
{
    constexpr int NTAP = K*K;
    const short8* ub = Wf + nh*4*64 + lane;
    short8 bA0 = ub[0], bA1 = ub[64], bA2 = ub[128], bA3 = ub[192];
    short8 bB0 = bA0, bB1 = bA1, bB2 = bA2, bB3 = bA3;
    { const short8* u = ub + 512; bB0=u[0]; bB1=u[64]; bB2=u[128]; bB3=u[192]; }
    #pragma unroll 1
    for (int tp = 0; tp < NTAP; tp += 2) {
        {
            int dy = tp / K, dx = tp % K;
            #pragma unroll
            for (int mt = 0; mt < MT2; ++mt) {
                short8 af = *(const short8*)((const char*)patch +
                    swz(((mh*MT2 + mt + dy)*PW + l15 + dx)*64 + g4*16));
                acc[mt][0] = __builtin_amdgcn_mfma_f32_16x16x32_bf16(af, bA0, acc[mt][0], 0,0,0);
                acc[mt][1] = __builtin_amdgcn_mfma_f32_16x16x32_bf16(af, bA1, acc[mt][1], 0,0,0);
                acc[mt][2] = __builtin_amdgcn_mfma_f32_16x16x32_bf16(af, bA2, acc[mt][2], 0,0,0);
                acc[mt][3] = __builtin_amdgcn_mfma_f32_16x16x32_bf16(af, bA3, acc[mt][3], 0,0,0);
            }
            if (tp + 2 < NTAP) { const short8* u = ub + (long)(tp+2)*512; bA0=u[0];bA1=u[64];bA2=u[128];bA3=u[192]; }
        }
        if (tp + 1 < NTAP) {
            int dy = (tp+1) / K, dx = (tp+1) % K;
            #pragma unroll
            for (int mt = 0; mt < MT2; ++mt) {
                short8 af = *(const short8*)((const char*)patch +
                    swz(((mh*MT2 + mt + dy)*PW + l15 + dx)*64 + g4*16));
                acc[mt][0] = __builtin_amdgcn_mfma_f32_16x16x32_bf16(af, bB0, acc[mt][0], 0,0,0);
                acc[mt][1] = __builtin_amdgcn_mfma_f32_16x16x32_bf16(af, bB1, acc[mt][1], 0,0,0);
                acc[mt][2] = __builtin_amdgcn_mfma_f32_16x16x32_bf16(af, bB2, acc[mt][2], 0,0,0);
                acc[mt][3] = __builtin_amdgcn_mfma_f32_16x16x32_bf16(af, bB3, acc[mt][3], 0,0,0);
            }
            if (tp + 3 < NTAP) { const short8* u = ub + (long)(tp+3)*512; bB0=u[0];bB1=u[64];bB2=u[128];bB3=u[192]; }
        }
    }
}

// ---------------- shared epilogue: LSTM gates + cell (frag-native) + h + pool/BN ----------------
template<int MT2>
__device__ __forceinline__ void lstm_epilogue(
    f32x4 (&acc)[MT2][4], unsigned short* hs, float* cst, unsigned short* plout,
    const float* gg, const float* bb, const float* mm, const float* vv,
    int H, int W, int n, int y0, int x0, int t, int mh, int nh, int l15, int g4, int first)
{
    const int f = nh*16 + l15;
    const int xt = x0 >> 4;
    const float sc = gg[f] * rsqrtf(vv[f] + 1e-3f);
    const float sh = bb[f] - mm[f]*sc;
    unsigned short* outh = hs + ((long)n*10 + t)*(long)H*W*32;
    float hv[MT2][4];
    #pragma unroll
    for (int mt = 0; mt < MT2; ++mt) {
        int row = y0 + mh*MT2 + mt;
        long tb = ((long)(n*H + row)*(W>>4) + xt)*512 + f*16 + g4*4;
        f32x4 cold = first ? (f32x4){0.f,0.f,0.f,0.f} : *(const f32x4*)&cst[tb];
        f32x4 cn;
        #pragma unroll
        for (int j = 0; j < 4; ++j) {
            float zi = acc[mt][0][j];
            float zf = acc[mt][1][j];
            float zg = acc[mt][2][j];
            float zo = acc[mt][3][j];
            float c2 = sigf(zf)*cold[j] + sigf(zi)*fmaxf(zg, 0.0f);
            cn[j] = c2;
            float h = sigf(zo)*fmaxf(c2, 0.0f);
            hv[mt][j] = h;
            outh[((long)row*W + (x0 + g4*4 + j))*32 + f] = f2bf(h);
        }
        *(f32x4*)&cst[tb] = cn;
    }
    #pragma unroll
    for (int mp = 0; mp < MT2/2; ++mp) {
        int orow = (y0>>1) + mh*(MT2/2) + mp;
        #pragma unroll
        for (int jp = 0; jp < 2; ++jp) {
            int ocol = (x0>>1) + g4*2 + jp;
            float mx = fmaxf(fmaxf(hv[2*mp][2*jp],   hv[2*mp][2*jp+1]),
                             fmaxf(hv[2*mp+1][2*jp], hv[2*mp+1][2*jp+1]));
            plout[(((long)(n*10 + t)*(H>>1) + orow)*(W>>1) + ocol)*32 + f] = f2bf(mx*sc + sh);
        }
    }
}

// ---------------- L1 step (TH=8): x patch -> LDS bf16, im2col scatter, dual MFMA conv ----------------
__device__ void l1_step(char* smem, const SP& p, int n, int y0, int x0, int t)
{
    constexpr int PAD = 2, PH = 12, PW = 20, MT2 = 4, MPX = 128;
    const int H = 64, W = 64;
    unsigned short* patch_s = (unsigned short*)smem;                 // 15360 B (h patch, swizzled)
    unsigned short* xpk_s   = (unsigned short*)(smem + 15360);       // 24576 B (im2col, swizzled)
    unsigned short* xraw    = (unsigned short*)(smem + 39936);       //  1440 B (x patch bf16)
    const int tid = threadIdx.x;
    const int lane = tid & 63, wid = tid >> 6;
    const int mh = wid >> 1, nh = wid & 1;
    const int l15 = lane & 15, g4 = lane >> 4;
    const int first = (t == 0);

    // zero-fill im2col buffer (pad k-slots 75..95 must be 0)
    short8 z8 = {0,0,0,0,0,0,0,0};
    #pragma unroll
    for (int c = tid; c < MPX*96/8; c += 256)
        ((short8*)xpk_s)[c] = z8;

    // x patch -> LDS bf16 (one global read per input value; coalesced)
    if (tid < PH*PW) {
        const float* xs = p.x + ((long)n*10 + t)*4096*3;
        int gy = y0 - PAD + tid / PW;
        int gx = x0 - PAD + tid % PW;
        float v0=0.f, v1=0.f, v2=0.f;
        if ((unsigned)gy < 64u && (unsigned)gx < 64u) {
            const float* b = xs + ((long)gy*64 + gx)*3;
            v0 = b[0]; v1 = b[1]; v2 = b[2];
        }
        xraw[tid*3]   = f2bf(v0);
        xraw[tid*3+1] = f2bf(v1);
        xraw[tid*3+2] = f2bf(v2);
    }

    // stage h patch (t>0)
    if (!first) {
        const unsigned short* s = p.hs1 + ((long)n*10 + (t-1))*(long)H*W*32;
        #pragma unroll 1
        for (int c = tid; c < PH*PW*4; c += 256) {
            int pix = c >> 2, gq = c & 3;
            int pr = pix / PW, pc = pix % PW;
            int gy = y0 - PAD + pr, gx = x0 - PAD + pc;
            short8 v = z8;
            if ((unsigned)gy < 64u && (unsigned)gx < 64u)
                v = *(const short8*)(s + ((long)gy*W + gx)*32 + gq*8);
            *(short8*)((char*)patch_s + swz(pix*64 + gq*16)) = v;
        }
    }
    __syncthreads();

    // im2col scatter: pure LDS->LDS, no bounds checks (OOB already zeroed in xraw)
    #pragma unroll 1
    for (int c = tid; c < MPX*25; c += 256) {
        int px = c & (MPX-1), tap = c >> 7;
        int dy = (tap*52) >> 8, dx = tap - dy*5;        // dy = tap/5
        int pi = ((px>>4) + dy)*PW + (px&15) + dx;
        int o = px*192 + tap*6;
        *(unsigned short*)((char*)xpk_s + swz(o))   = xraw[pi*3];
        *(unsigned short*)((char*)xpk_s + swz(o+2)) = xraw[pi*3+1];
        *(unsigned short*)((char*)xpk_s + swz(o+4)) = xraw[pi*3+2];
    }
    __syncthreads();

    f32x4 acc[MT2][4];
    #pragma unroll
    for (int ntl = 0; ntl < 4; ++ntl) {
        float bv = p.bp[(nh*4+ntl)*16 + l15];
        #pragma unroll
        for (int mt = 0; mt < MT2; ++mt)
            acc[mt][ntl] = (f32x4){bv,bv,bv,bv};
    }
    // x-conv: 3 padded K-chunks
    #pragma unroll 1
    for (int c = 0; c < 3; ++c) {
        const short8* wp = p.W1b + ((long)c*8 + nh*4)*64 + lane;
        short8 bf0 = wp[0], bf1 = wp[64], bf2 = wp[128], bf3 = wp[192];
        #pragma unroll
        for (int mt = 0; mt < MT2; ++mt) {
            short8 af = *(const short8*)((const char*)xpk_s +
                swz(((mh*MT2+mt)*16 + l15)*192 + c*64 + g4*16));
            acc[mt][0] = __builtin_amdgcn_mfma_f32_16x16x32_bf16(af, bf0, acc[mt][0], 0,0,0);
            acc[mt][1] = __builtin_amdgcn_mfma_f32_16x16x32_bf16(af, bf1, acc[mt][1], 0,0,0);
            acc[mt][2] = __builtin_amdgcn_mfma_f32_16x16x32_bf16(af, bf2, acc[mt][2], 0,0,0);
            acc[mt][3] = __builtin_amdgcn_mfma_f32_16x16x32_bf16(af, bf3, acc[mt][3], 0,0,0);
        }
    }
    if (!first)
        conv_taps<5,PW,MT2>(acc, patch_s, p.U1b, mh, nh, l15, g4, lane);

    lstm_epilogue<MT2>(acc, p.hs1, p.cst1, p.pl1, p.g1, p.be1, p.m1, p.v1,
                       H, W, n, y0, x0, t, mh, nh, l15, g4, first);
}

// ---------------- L2/L3 step: dual conv (W ⊛ pooled_prev + U ⊛ h_prev) + gates ----------------
template<int K, int HH>
__device__ void l23_step(char* smem, const SP& p,
    unsigned short* hs, const unsigned short* plin, unsigned short* plout, float* cst,
    const short8* Ufr, const short8* Wfr, const float* bp,
    const float* gg, const float* bb, const float* mm, const float* vv,
    int n, int y0, int x0, int t)
{
    constexpr int TH = 4, PAD = K/2, PH = TH+K-1, PW = 16+K-1, MT2 = 2;
    const int H = HH, W = HH;
    unsigned short* patchH = (unsigned short*)smem;
    unsigned short* patchX = (unsigned short*)(smem + PH*PW*64);

    const int tid = threadIdx.x;
    const int lane = tid & 63, wid = tid >> 6;
    const int mh = wid >> 1, nh = wid & 1;
    const int l15 = lane & 15, g4 = lane >> 4;
    const int first = (t == 0);

    const unsigned short* hsrc = hs + ((long)n*10 + (t-1))*(long)H*W*32;
    const unsigned short* xsrc = plin + ((long)n*10 + t)*(long)H*W*32;
    short8 z8 = {0,0,0,0,0,0,0,0};
    #pragma unroll 1
    for (int c = tid; c < PH*PW*4; c += 256) {
        int pix = c >> 2, gq = c & 3;
        int pr = pix / PW, pc = pix % PW;
        int gy = y0 - PAD + pr, gx = x0 - PAD + pc;
        short8 vx = z8, vh = z8;
        if ((unsigned)gy < (unsigned)H && (unsigned)gx < (unsigned)W) {
            vx = *(const short8*)(xsrc + ((long)gy*W + gx)*32 + gq*8);
            if (!first) vh = *(const short8*)(hsrc + ((long)gy*W + gx)*32 + gq*8);
        }
        *(short8*)((char*)patchX + swz(pix*64 + gq*16)) = vx;
        *(short8*)((char*)patchH + swz(pix*64 + gq*16)) = vh;
    }
    __syncthreads();

    f32x4 acc[MT2][4];
    #pragma unroll
    for (int ntl = 0; ntl < 4; ++ntl) {
        float bv = bp[(nh*4+ntl)*16 + l15];
        #pragma unroll
        for (int mt = 0; mt < MT2; ++mt)
            acc[mt][ntl] = (f32x4){bv,bv,bv,bv};
    }
    conv_taps<K,PW,MT2>(acc, patchX, Wfr, mh, nh, l15, g4, lane);
    if (!first) conv_taps<K,PW,MT2>(acc, patchH, Ufr, mh, nh, l15, g4, lane);

    lstm_epilogue<MT2>(acc, hs, cst, plout, gg, bb, mm, vv,
                       H, W, n, y0, x0, t, mh, nh, l15, g4, first);
}

// ---------------- pipelined stage kernel: L1[s] | L2[s-1] | L3[s-2] (R6 ordering) ----------------
__global__ __launch_bounds__(256)
void stage_k(SP p, int s)
{
    __shared__ __align__(16) char smem[41472];
    const int bid = blockIdx.x;
    if (bid < 256) {
        int t = s;
        if (t < 10) {
            int n = bid >> 5, rem = bid & 31;
            l1_step(smem, p, n, (rem >> 2)*8, (rem & 3)*16, t);
        }
    } else if (bid < 384) {
        int t = s - 1;
        if (t >= 0 && t < 10) {
            int idx = bid - 256;
            int n = idx >> 4, rem = idx & 15;
            l23_step<5,32>(smem, p, p.hs2, p.pl1, p.pl2, p.cst2,
                           p.U2b, p.W2b, p.bp + 128,
                           p.g2, p.be2, p.m2, p.v2,
                           n, (rem >> 1)*4, (rem & 1)*16, t);
        } else if (s == 0 && bid == 256 && threadIdx.x == 0) {
            __hip_atomic_store(p.ctr, 0u, __ATOMIC_RELEASE, __HIP_MEMORY_SCOPE_AGENT);
        }
    } else {
        int t = s - 2;
        if (t >= 0 && t < 10) {
            int idx = bid - 384;
            int n = idx >> 2, rem = idx & 3;
            l23_step<3,16>(smem, p, p.hs3, p.pl2, p.pl3, p.cst3,
                           p.U3b, p.W3b, p.bp + 256,
                           p.g3, p.be3, p.m3, p.v3,
                           n, rem*4, 0, t);
        }
    }
}

// ---------------- dense: K-split partial GEMM + last-block tail ----------------
__global__ __launch_bounds__(256)
void dense_all(const unsigned short* __restrict__ flat, const float* __restrict__ Wd1,
               const float* __restrict__ bd1, const float* __restrict__ Wd2,
               const float* __restrict__ bd2, float* __restrict__ partial,
               unsigned* __restrict__ ctr, float* __restrict__ outp)
{
    __shared__ __align__(16) float xs[2048];
    __shared__ unsigned rank_s;
    const int kc = blockIdx.x, k0 = kc*256;
    const int t = threadIdx.x;
    {
        int r = t >> 5, kb = (t & 31)*8;
        short8 v = *(const short8*)(flat + (long)r*20480 + k0 + kb);
        #pragma unroll
        for (int e = 0; e < 8; ++e) xs[(kb+e)*8 + r] = bf2f((unsigned short)v[e]);
    }
    __syncthreads();
    const int c = t & 63, seg = t >> 6;
    f32x4 accA = {0,0,0,0}, accB = {0,0,0,0};
    #pragma unroll 4
    for (int kk = seg*64; kk < seg*64 + 64; ++kk) {
        float w = Wd1[(long)(k0+kk)*64 + c];
        f32x4 xa = *(const f32x4*)&xs[kk*8];
        f32x4 xb = *(const f32x4*)&xs[kk*8 + 4];
        #pragma unroll
        for (int j = 0; j < 4; ++j) { accA[j] = fmaf(xa[j], w, accA[j]); accB[j] = fmaf(xb[j], w, accB[j]); }
    }
    __syncthreads();
    #pragma unroll
    for (int j = 0; j < 4; ++j) {
        xs[(seg*8 + j)*64 + c]     = accA[j];
        xs[(seg*8 + 4 + j)*64 + c] = accB[j];
    }
    __syncthreads();
    #pragma unroll
    for (int o = t; o < 512; o += 256) {
        int r = o >> 6, cc = o & 63;
        partial[(long)kc*512 + o] = (xs[(0*8+r)*64+cc] + xs[(1*8+r)*64+cc])
                                  + (xs[(2*8+r)*64+cc] + xs[(3*8+r)*64+cc]);
    }
    __syncthreads();
    if (t == 0) {
        __builtin_amdgcn_fence(__ATOMIC_RELEASE, "agent");
        rank_s = __hip_atomic_fetch_add(ctr, 1u, __ATOMIC_ACQ_REL, __HIP_MEMORY_SCOPE_AGENT);
    }
    __syncthreads();
    if (rank_s != 79) return;
    __builtin_amdgcn_fence(__ATOMIC_ACQUIRE, "agent");

    float* d1  = xs;            // 512
    float* l2s = xs + 512;      // 80
    #pragma unroll
    for (int rr = 0; rr < 2; ++rr) {
        int idx = rr*256 + t;
        int cc = idx & 63;
        float s = bd1[cc];
        #pragma unroll 4
        for (int q = 0; q < 80; ++q) s += partial[q*512 + idx];
        float mx = s;
        for (int o = 32; o > 0; o >>= 1) mx = fmaxf(mx, __shfl_xor(mx, o, 64));
        float e = __expf(s - mx);
        float sm = e;
        for (int o = 32; o > 0; o >>= 1) sm += __shfl_xor(sm, o, 64);
        d1[idx] = e / sm;
    }
    __syncthreads();
    if (t < 80) {
        int r = t / 10, o = t % 10;
        float l = bd2[o];
        #pragma unroll 8
        for (int cc = 0; cc < 64; ++cc) l = fmaf(d1[r*64 + cc], Wd2[cc*10 + o], l);
        l2s[t] = l;
    }
    __syncthreads();
    if (t < 8) {
        float mx2 = l2s[t*10];
        #pragma unroll
        for (int j = 1; j < 10; ++j) mx2 = fmaxf(mx2, l2s[t*10 + j]);
        float ev[10], s2 = 0.f;
        #pragma unroll
        for (int j = 0; j < 10; ++j) { ev[j] = __expf(l2s[t*10 + j] - mx2); s2 += ev[j]; }
        #pragma unroll
        for (int j = 0; j < 10; ++j) outp[t*10 + j] = ev[j] / s2;
    }
}

extern "C" void kernel_launch(void* const* d_in, const int* in_sizes, int n_in,
                              void* d_out, int out_size, void* d_ws, size_t ws_size,
                              hipStream_t stream)
{
    const float* Wd1 = (const float*)d_in[22];
    const float* bd1 = (const float*)d_in[23];
    const float* Wd2 = (const float*)d_in[24];
    const float* bd2 = (const float*)d_in[25];

    char* ws = (char*)d_ws;
    SP p;
    p.x   = (const float*)d_in[0];
    p.g1  = (const float*)d_in[4];  p.be1 = (const float*)d_in[5];  p.m1 = (const float*)d_in[6];  p.v1 = (const float*)d_in[7];
    p.g2  = (const float*)d_in[11]; p.be2 = (const float*)d_in[12]; p.m2 = (const float*)d_in[13]; p.v2 = (const float*)d_in[14];
    p.g3  = (const float*)d_in[18]; p.be3 = (const float*)d_in[19]; p.m3 = (const float*)d_in[20]; p.v3 = (const float*)d_in[21];

    p.hs1 = (unsigned short*)(ws);                  // 20,971,520
    p.hs2 = (unsigned short*)(ws + 20971520);       //  5,242,880
    p.hs3 = (unsigned short*)(ws + 26214400);       //  1,310,720
    p.cst1 = (float*)(ws + 27525120);               //  4,194,304
    p.cst2 = (float*)(ws + 31719424);               //  1,048,576
    p.cst3 = (float*)(ws + 32768000);               //    262,144
    p.pl1 = (unsigned short*)(ws + 33030144);       //  5,242,880
    p.pl2 = (unsigned short*)(ws + 38273024);       //  1,310,720
    p.pl3 = (unsigned short*)(ws + 39583744);       //    327,680
    short8* U1b = (short8*)(ws + 39911424);         //    204,800
    short8* W1b = (short8*)(ws + 40116224);         //     24,576
    short8* U2b = (short8*)(ws + 40140800);         //    204,800
    short8* W2b = (short8*)(ws + 40345600);         //    204,800
    short8* U3b = (short8*)(ws + 40550400);         //     73,728
    short8* W3b = (short8*)(ws + 40624128);         //     73,728
    float*  bp  = (float*)(ws + 40697856);          //      1,536
    float*  partial = (float*)(ws + 40699392);      //    163,840
    p.ctr = (unsigned*)(ws + 40863232);             //     64 B
    p.U1b = U1b; p.W1b = W1b; p.U2b = U2b; p.W2b = W2b; p.U3b = U3b; p.W3b = W3b;
    p.bp = bp;

    xform_all<<<194, 256, 0, stream>>>(
        (const float*)d_in[2], (const float*)d_in[1],
        (const float*)d_in[9], (const float*)d_in[8],
        (const float*)d_in[16], (const float*)d_in[15],
        (const float*)d_in[3], (const float*)d_in[10], (const float*)d_in[17],
        U1b, W1b, U2b, W2b, U3b, W3b, bp);

    for (int s = 0; s < 12; ++s)
        stage_k<<<416, 256, 0, stream>>>(p, s);

    dense_all<<<80, 256, 0, stream>>>(p.pl3, Wd1, bd1, Wd2, bd2, partial,
                                      p.ctr, (float*)d_out);
}